// Round 3
// baseline (1097.998 us; speedup 1.0000x reference)
//
#include <hip/hip_runtime.h>
#include <math.h>

#define MULC 256
#define ROWF 2304   // 9*MUL floats per node row

typedef float f32x4 __attribute__((ext_vector_type(4)));

// ---------------------------------------------------------------------------
// Fused kernel (R2): no workspace, single launch.
//  Step 1: each block folds W_lin @ W_tp into LDS wf[2304] itself.
//    thread t (= u) walks rows Wl0/1/2[u,:] (L1-cached: 8KB/wave window),
//    dots against Wt0/1/2 (uniform address -> scalar loads). ~768 fma/thread,
//    W matrices (768 KB) are L2-resident after first touch. Cost ~+5-10 us.
//  Step 2: streaming loop = byte-identical to the proven 733us kernel
//    (nontemporal loads, single acc chain), with w4[] sourced from LDS.
//  Purpose: (a) test whether the 2.4GB per-iteration ws-poison fill
//    (375 us, inside the timed window) is conditional on d_ws usage;
//    (b) push the fused kernel's duration into the rocprof top-5 so we
//    finally see its FETCH_SIZE / Occupancy / VALUBusy.
// ---------------------------------------------------------------------------
__global__ __launch_bounds__(256) void energy_fused_kernel(
    const float* __restrict__ x, const float* __restrict__ charges,
    const float* __restrict__ Wl0, const float* __restrict__ Wl1,
    const float* __restrict__ Wl2, const float* __restrict__ Wt0,
    const float* __restrict__ Wt1, const float* __restrict__ Wt2,
    float* __restrict__ out, int n_rows, int n_waves) {
  __shared__ __align__(16) float wf[ROWF];

  const int t    = threadIdx.x;   // 0..255, doubles as u
  const int lane = t & 63;

  // ---- step 1: in-block weight fold into LDS ----
  {
    const f32x4* __restrict__ r0 = (const f32x4*)(Wl0 + t * MULC);
    const f32x4* __restrict__ r1 = (const f32x4*)(Wl1 + t * MULC);
    const f32x4* __restrict__ r2 = (const f32x4*)(Wl2 + t * MULC);
    const f32x4* __restrict__ t0 = (const f32x4*)Wt0;
    const f32x4* __restrict__ t1 = (const f32x4*)Wt1;
    const f32x4* __restrict__ t2 = (const f32x4*)Wt2;
    float s0 = 0.f, s1 = 0.f, s2 = 0.f;
#pragma unroll 8
    for (int k = 0; k < MULC / 4; ++k) {
      const f32x4 a0 = r0[k], a1 = r1[k], a2 = r2[k];
      const f32x4 b0 = t0[k], b1 = t1[k], b2 = t2[k];
      s0 = fmaf(a0.x, b0.x, s0); s0 = fmaf(a0.y, b0.y, s0);
      s0 = fmaf(a0.z, b0.z, s0); s0 = fmaf(a0.w, b0.w, s0);
      s1 = fmaf(a1.x, b1.x, s1); s1 = fmaf(a1.y, b1.y, s1);
      s1 = fmaf(a1.z, b1.z, s1); s1 = fmaf(a1.w, b1.w, s1);
      s2 = fmaf(a2.x, b2.x, s2); s2 = fmaf(a2.y, b2.y, s2);
      s2 = fmaf(a2.z, b2.z, s2); s2 = fmaf(a2.w, b2.w, s2);
    }
    const float base = 0.0625f / sqrtf(768.0f);  // lin_norm * alpha
    wf[t] = s0 * base;
    const float sv1 = s1 * base * (1.0f / sqrtf(3.0f));
#pragma unroll
    for (int i = 0; i < 3; ++i) wf[256 + t * 3 + i] = sv1;
    const float sv2 = s2 * base * (1.0f / sqrtf(5.0f));
#pragma unroll
    for (int i = 0; i < 5; ++i) wf[1024 + t * 5 + i] = sv2;
  }
  __syncthreads();

  // ---- per-lane static setup (w4 from LDS; cpack computed) ----
  f32x4 w4[9];
  int cpack[9];  // 4 packed byte-addresses (cidx*4) per int
#pragma unroll
  for (int j = 0; j < 9; ++j) {
    const int f = lane + 64 * j;
    w4[j] = ((const f32x4*)wf)[f];
    int p = 0;
#pragma unroll
    for (int m = 0; m < 4; ++m) {
      const int e = 4 * f + m;
      int c;
      if (e < 256)       c = 0;
      else if (e < 1024) c = 1 + (e - 256) % 3;
      else               c = 4 + (e - 1024) % 5;
      p |= (c * 4) << (8 * m);
    }
    cpack[j] = p;
  }

  const int wave = (int)((blockIdx.x * blockDim.x + threadIdx.x) >> 6);
  if (wave >= n_rows) return;

  // prime the charge pipeline for the first row
  float chv = 0.f;
  if (lane < 9) chv = charges[(size_t)wave * 9 + lane];

  for (int z = wave; z < n_rows; z += n_waves) {
    const int chvi = __float_as_int(chv);
    const float c0 = __int_as_float(__builtin_amdgcn_readfirstlane(chvi));

    // prefetch next row's charges (independent of this row's compute)
    const int zn = z + n_waves;
    float chv_next = 0.f;
    if (zn < n_rows && lane < 9) chv_next = charges[(size_t)zn * 9 + lane];

    const f32x4* __restrict__ xr = (const f32x4*)(x + (size_t)z * ROWF);
    float acc = 0.f;

    // ---- j = 0: all elements use charge component 0 (SGPR broadcast) ----
    {
      const f32x4 v = __builtin_nontemporal_load(&xr[lane]);
      acc = fmaf(v.x, w4[0].x * c0, acc);
      acc = fmaf(v.y, w4[0].y * c0, acc);
      acc = fmaf(v.z, w4[0].z * c0, acc);
      acc = fmaf(v.w, w4[0].w * c0, acc);
    }
    // ---- j = 1..3 (x1 region): charge of m=3 equals charge of m=0 ----
#pragma unroll
    for (int j = 1; j < 4; ++j) {
      const f32x4 v = __builtin_nontemporal_load(&xr[lane + 64 * j]);
      const int p = cpack[j];
      const float ca = __int_as_float(__builtin_amdgcn_ds_bpermute(p & 0xff, chvi));
      const float cb = __int_as_float(__builtin_amdgcn_ds_bpermute((p >> 8) & 0xff, chvi));
      const float cc = __int_as_float(__builtin_amdgcn_ds_bpermute((p >> 16) & 0xff, chvi));
      acc = fmaf(v.x, w4[j].x * ca, acc);
      acc = fmaf(v.y, w4[j].y * cb, acc);
      acc = fmaf(v.z, w4[j].z * cc, acc);
      acc = fmaf(v.w, w4[j].w * ca, acc);  // m=3 shares m=0's charge (mod 3)
    }
    // ---- j = 4..8 (x2 region): 4 distinct charges per float4 (mod 5) ----
#pragma unroll
    for (int j = 4; j < 9; ++j) {
      const f32x4 v = __builtin_nontemporal_load(&xr[lane + 64 * j]);
      const int p = cpack[j];
      const float ca = __int_as_float(__builtin_amdgcn_ds_bpermute(p & 0xff, chvi));
      const float cb = __int_as_float(__builtin_amdgcn_ds_bpermute((p >> 8) & 0xff, chvi));
      const float cc = __int_as_float(__builtin_amdgcn_ds_bpermute((p >> 16) & 0xff, chvi));
      const float cd = __int_as_float(__builtin_amdgcn_ds_bpermute((p >> 24) & 0xff, chvi));
      acc = fmaf(v.x, w4[j].x * ca, acc);
      acc = fmaf(v.y, w4[j].y * cb, acc);
      acc = fmaf(v.z, w4[j].z * cc, acc);
      acc = fmaf(v.w, w4[j].w * cd, acc);
    }

    // wave-level sum
#pragma unroll
    for (int off = 32; off > 0; off >>= 1) acc += __shfl_down(acc, off, 64);
    if (lane == 0) out[z] = acc;

    chv = chv_next;
  }
}

extern "C" void kernel_launch(void* const* d_in, const int* in_sizes, int n_in,
                              void* d_out, int out_size, void* d_ws, size_t ws_size,
                              hipStream_t stream) {
  const float* node_feats = (const float*)d_in[0];
  const float* charges    = (const float*)d_in[1];
  const float* W_lin0     = (const float*)d_in[2];
  const float* W_lin1     = (const float*)d_in[3];
  const float* W_lin2     = (const float*)d_in[4];
  const float* W_tp0      = (const float*)d_in[5];
  const float* W_tp1      = (const float*)d_in[6];
  const float* W_tp2      = (const float*)d_in[7];
  float* out = (float*)d_out;
  (void)d_ws; (void)ws_size;  // workspace intentionally unused (R2 experiment)

  const int n_rows = in_sizes[0] / ROWF;

  const int blocks  = 4096;            // 16384 waves -> 4 rows/wave at N=65536
  const int n_waves = blocks * (256 / 64);
  energy_fused_kernel<<<blocks, 256, 0, stream>>>(
      node_feats, charges, W_lin0, W_lin1, W_lin2, W_tp0, W_tp1, W_tp2,
      out, n_rows, n_waves);
}

// Round 5
// 731.383 us; speedup vs baseline: 1.5013x; 1.5013x over previous
//
#include <hip/hip_runtime.h>
#include <math.h>

#define MULC 256
#define ROWF 2304   // 9*MUL floats per node row

typedef float f32x4 __attribute__((ext_vector_type(4)));

// ---------------------------------------------------------------------------
// Kernel 1: fold W_lin @ W_tp into a single expanded weight vector W_full[2304]
//   (unchanged from the 733us baseline; i-duplicated values per u-group)
// ---------------------------------------------------------------------------
__global__ __launch_bounds__(64) void build_wfull_kernel(
    const float* __restrict__ Wl0, const float* __restrict__ Wl1,
    const float* __restrict__ Wl2, const float* __restrict__ Wt0,
    const float* __restrict__ Wt1, const float* __restrict__ Wt2,
    float* __restrict__ wfull) {
  const int b    = blockIdx.x;
  const int mat  = b >> 8;
  const int u    = b & 255;
  const int lane = threadIdx.x;  // 0..63

  const float* __restrict__ Wl = (mat == 0) ? Wl0 : (mat == 1) ? Wl1 : Wl2;
  const float* __restrict__ Wt = (mat == 0) ? Wt0 : (mat == 1) ? Wt1 : Wt2;

  float s = 0.f;
#pragma unroll
  for (int t = 0; t < 4; ++t) {
    const int v = lane + 64 * t;
    s = fmaf(Wl[u * MULC + v], Wt[v], s);
  }
#pragma unroll
  for (int off = 32; off > 0; off >>= 1) s += __shfl_down(s, off, 64);

  if (lane == 0) {
    const float base = 0.0625f / sqrtf(768.0f);  // lin_norm * alpha
    if (mat == 0) {
      wfull[u] = s * base;
    } else if (mat == 1) {
      const float sv = s * base * (1.0f / sqrtf(3.0f));
#pragma unroll
      for (int i = 0; i < 3; ++i) wfull[256 + u * 3 + i] = sv;
    } else {
      const float sv = s * base * (1.0f / sqrtf(5.0f));
#pragma unroll
      for (int i = 0; i < 5; ++i) wfull[1024 + u * 5 + i] = sv;
    }
  }
}

// ---------------------------------------------------------------------------
// Row partial: accumulate x.w into ROTATED per-cidx accumulator banks.
//   R3 counters showed the old kernel latency-bound (VALUBusy 8.7%, HBM 8%):
//   29 bpermutes + 36 muls per row sat in the load-consume chain, so waves
//   spent ~4500 cyc/row NOT issuing memory. New scheme:
//   For float4 chunk k=l+64j, element m:
//     x1 region (j=1..3): cidx-1 = (l + j + m - 1) mod 3  -> slot (j+m-1)%3
//       of a (l mod 3)-rotated bank a1[3].
//     x2 region (j=4..8): cidx-4 = (4l + j + m - 4) mod 5 -> slot (j+m-4)%5
//       of a ((4l) mod 5)-rotated bank a2[5].
//   wfull values are i-independent per u-group, so the SAME w4[j][m] weights
//   apply unchanged. Zero DS ops and zero charge-muls in the stream loop;
//   un-rotation = 8 bpermutes + 9 fma once per row in the epilogue.
// ---------------------------------------------------------------------------
__device__ __forceinline__ float row_partial(
    const f32x4* __restrict__ xr, int lane, const f32x4* w4,
    const int* bp1, const int* bp2, int chvi) {
  float a0 = 0.f;
  float a1[3] = {0.f, 0.f, 0.f};
  float a2[5] = {0.f, 0.f, 0.f, 0.f, 0.f};

  // j = 0: x0 region, all cidx 0
  {
    const f32x4 v = __builtin_nontemporal_load(&xr[lane]);
    a0 = fmaf(v.x, w4[0].x, a0);
    a0 = fmaf(v.y, w4[0].y, a0);
    a0 = fmaf(v.z, w4[0].z, a0);
    a0 = fmaf(v.w, w4[0].w, a0);
  }
  // j = 1..3: x1 region -> rotated 3-bank
#pragma unroll
  for (int j = 1; j < 4; ++j) {
    const f32x4 v = __builtin_nontemporal_load(&xr[lane + 64 * j]);
    { const int s = (j - 1) % 3; a1[s] = fmaf(v.x, w4[j].x, a1[s]); }
    { const int s = (j    ) % 3; a1[s] = fmaf(v.y, w4[j].y, a1[s]); }
    { const int s = (j + 1) % 3; a1[s] = fmaf(v.z, w4[j].z, a1[s]); }
    { const int s = (j + 2) % 3; a1[s] = fmaf(v.w, w4[j].w, a1[s]); }
  }
  // j = 4..8: x2 region -> rotated 5-bank
#pragma unroll
  for (int j = 4; j < 9; ++j) {
    const f32x4 v = __builtin_nontemporal_load(&xr[lane + 64 * j]);
    { const int s = (j - 4) % 5; a2[s] = fmaf(v.x, w4[j].x, a2[s]); }
    { const int s = (j - 3) % 5; a2[s] = fmaf(v.y, w4[j].y, a2[s]); }
    { const int s = (j - 2) % 5; a2[s] = fmaf(v.z, w4[j].z, a2[s]); }
    { const int s = (j - 1) % 5; a2[s] = fmaf(v.w, w4[j].w, a2[s]); }
  }

  // epilogue: un-rotate via per-lane precomputed bpermute addresses
  const float c0 = __int_as_float(__builtin_amdgcn_readfirstlane(chvi));
  float t = a0 * c0;
#pragma unroll
  for (int s = 0; s < 3; ++s)
    t = fmaf(a1[s],
             __int_as_float(__builtin_amdgcn_ds_bpermute(bp1[s], chvi)), t);
#pragma unroll
  for (int s = 0; s < 5; ++s)
    t = fmaf(a2[s],
             __int_as_float(__builtin_amdgcn_ds_bpermute(bp2[s], chvi)), t);
  return t;
}

// ---------------------------------------------------------------------------
// Kernel 2: streaming weighted reduction, one wave per row, 2-row unroll
// (18 KB in flight per wave). DS/row: 8 bpermute + 6 reduce (was 35).
// ---------------------------------------------------------------------------
__global__ __launch_bounds__(256) void energy_kernel(
    const float* __restrict__ x, const float* __restrict__ charges,
    const float* __restrict__ wfull, float* __restrict__ out,
    int n_rows, int n_waves) {
  const int lane = threadIdx.x & 63;
  const int wave = (int)((blockIdx.x * blockDim.x + threadIdx.x) >> 6);

  // ---- loop-invariant per-lane setup ----
  f32x4 w4[9];
#pragma unroll
  for (int j = 0; j < 9; ++j) w4[j] = ((const f32x4*)wfull)[lane + 64 * j];

  int bp1[3], bp2[5];
  {
    const int r3 = lane % 3;
    const int r5 = (4 * lane) % 5;
#pragma unroll
    for (int s = 0; s < 3; ++s) bp1[s] = 4 * (1 + (s + r3) % 3);
#pragma unroll
    for (int s = 0; s < 5; ++s) bp2[s] = 4 * (4 + (s + r5) % 5);
  }

  if (wave >= n_rows) return;

  for (int z = wave; z < n_rows; z += 2 * n_waves) {
    const int zB = z + n_waves;
    const bool hasB = (zB < n_rows);

    float chvA = 0.f, chvB = 0.f;
    if (lane < 9) {
      chvA = charges[(size_t)z * 9 + lane];
      if (hasB) chvB = charges[(size_t)zB * 9 + lane];
    }

    const f32x4* __restrict__ xrA = (const f32x4*)(x + (size_t)z * ROWF);
    float tA = row_partial(xrA, lane, w4, bp1, bp2, __float_as_int(chvA));

    float tB = 0.f;
    if (hasB) {
      const f32x4* __restrict__ xrB = (const f32x4*)(x + (size_t)zB * ROWF);
      tB = row_partial(xrB, lane, w4, bp1, bp2, __float_as_int(chvB));
    }

    // wave-level sums (A and B reduces interleave; latencies overlap)
#pragma unroll
    for (int off = 32; off > 0; off >>= 1) {
      tA += __shfl_down(tA, off, 64);
      tB += __shfl_down(tB, off, 64);
    }
    if (lane == 0) {
      out[z] = tA;
      if (hasB) out[zB] = tB;
    }
  }
}

extern "C" void kernel_launch(void* const* d_in, const int* in_sizes, int n_in,
                              void* d_out, int out_size, void* d_ws, size_t ws_size,
                              hipStream_t stream) {
  const float* node_feats = (const float*)d_in[0];
  const float* charges    = (const float*)d_in[1];
  const float* W_lin0     = (const float*)d_in[2];
  const float* W_lin1     = (const float*)d_in[3];
  const float* W_lin2     = (const float*)d_in[4];
  const float* W_tp0      = (const float*)d_in[5];
  const float* W_tp1      = (const float*)d_in[6];
  const float* W_tp2      = (const float*)d_in[7];
  float* out   = (float*)d_out;
  float* wfull = (float*)d_ws;  // 2304 floats = 9216 B of scratch

  const int n_rows = in_sizes[0] / ROWF;

  build_wfull_kernel<<<3 * 256, 64, 0, stream>>>(W_lin0, W_lin1, W_lin2,
                                                 W_tp0, W_tp1, W_tp2, wfull);

  const int blocks  = 4096;            // 16384 waves -> 4 rows/wave at N=65536
  const int n_waves = blocks * (256 / 64);
  energy_kernel<<<blocks, 256, 0, stream>>>(node_feats, charges, wfull, out,
                                            n_rows, n_waves);
}